// Round 1
// baseline (35875.223 us; speedup 1.0000x reference)
//
#include <hip/hip_runtime.h>
#include <math.h>

#define BZ 4096
#define NT 128
#define DH 128
#define DI 32

// ---------------- scores: S_part[p] = sum over block p's 64 batch rows of outer(h_b, e_b)
template<int D>
__global__ __launch_bounds__(256) void k_scores(const float* __restrict__ hsrc,
                                                const float* __restrict__ enc,
                                                int t, float* __restrict__ spart) {
  __shared__ float hs[64][D + 1];
  __shared__ float es[64][DH + 1];
  const int p = blockIdx.x, tid = threadIdx.x;
  const int b0 = p * 64;
  for (int idx = tid; idx < 64 * D; idx += 256) {
    int r = idx / D, c = idx % D;
    hs[r][c] = hsrc[(size_t)(b0 + r) * D + c];
  }
  for (int idx = tid; idx < 64 * DH; idx += 256) {
    int r = idx >> 7, c = idx & 127;
    es[r][c] = enc[((size_t)(b0 + r) * NT + t) * DH + c];
  }
  __syncthreads();
  constexpr int TI = D / 16;
  const int ti = tid >> 4, tj = tid & 15;
  float acc[TI][8];
#pragma unroll
  for (int i = 0; i < TI; ++i)
#pragma unroll
    for (int j = 0; j < 8; ++j) acc[i][j] = 0.f;
  for (int b = 0; b < 64; ++b) {
    float ha[TI], eb[8];
#pragma unroll
    for (int i = 0; i < TI; ++i) ha[i] = hs[b][ti + 16 * i];
#pragma unroll
    for (int j = 0; j < 8; ++j) eb[j] = es[b][tj + 16 * j];
#pragma unroll
    for (int i = 0; i < TI; ++i)
#pragma unroll
      for (int j = 0; j < 8; ++j) acc[i][j] += ha[i] * eb[j];
  }
#pragma unroll
  for (int i = 0; i < TI; ++i)
#pragma unroll
    for (int j = 0; j < 8; ++j)
      spart[((size_t)p * D + (ti + 16 * i)) * DH + (tj + 16 * j)] = acc[i][j];
}

// ---------------- reduce 64 partials + row softmax -> W (R x 128)
template<int R>
__global__ __launch_bounds__(128) void k_softmax(const float* __restrict__ spart,
                                                 float* __restrict__ W) {
  const int r = blockIdx.x, j = threadIdx.x;
  float s = 0.f;
  for (int p = 0; p < 64; ++p) s += spart[((size_t)p * R + r) * DH + j];
  __shared__ float xm[2], xs[2];
  float m = s;
  for (int o = 1; o < 64; o <<= 1) m = fmaxf(m, __shfl_xor(m, o));
  if ((j & 63) == 0) xm[j >> 6] = m;
  __syncthreads();
  m = fmaxf(xm[0], xm[1]);
  float e = expf(s - m);
  float sum = e;
  for (int o = 1; o < 64; o <<= 1) sum += __shfl_xor(sum, o);
  if ((j & 63) == 0) xs[j >> 6] = sum;
  __syncthreads();
  sum = xs[0] + xs[1];
  W[r * DH + j] = e / sum;
}

// ---------------- main step t>=1: context -> attend(tanh) -> GRU2 -> h, out[:,t,:]
__global__ __launch_bounds__(256) void k_main(
    const float* __restrict__ enc, int t,
    const float* __restrict__ Wm,
    const float* __restrict__ A2, const float* __restrict__ b2,
    const float* __restrict__ wih, const float* __restrict__ whh,
    const float* __restrict__ bih, const float* __restrict__ bhh,
    const float* __restrict__ outw, const float* __restrict__ outb,
    float* __restrict__ h, float* __restrict__ out) {
  __shared__ float Wl[DH][DH + 1];     // 66 KB
  __shared__ float el[16][DH + 1];
  __shared__ float hl[16][DH + 1];
  __shared__ float cl[16][DH + 1];
  __shared__ float al[16][DH + 1];
  __shared__ float hn[16][DH + 1];
  const int b0 = blockIdx.x * 16, tid = threadIdx.x;
  for (int idx = tid; idx < DH * DH; idx += 256) Wl[idx >> 7][idx & 127] = Wm[idx];
  for (int idx = tid; idx < 16 * DH; idx += 256) {
    int r = idx >> 7, c = idx & 127;
    el[r][c] = enc[((size_t)(b0 + r) * NT + t) * DH + c];
    hl[r][c] = h[(size_t)(b0 + r) * DH + c];
  }
  __syncthreads();
  const int r = tid >> 4, ci = tid & 15;
  // context[r][i] = sum_j W[i][j] * e[r][j]
#pragma unroll
  for (int ii = 0; ii < 8; ++ii) {
    const int i = ci + 16 * ii;
    float acc = 0.f;
#pragma unroll 4
    for (int j = 0; j < DH; ++j) acc += Wl[i][j] * el[r][j];
    cl[r][i] = acc;
  }
  __syncthreads();
  // a[r][i] = tanh(att2_w[i,:256] . [ctx, h] + b2[i])
#pragma unroll
  for (int ii = 0; ii < 8; ++ii) {
    const int i = ci + 16 * ii;
    float acc = b2[i];
    const float* Ar = A2 + (size_t)i * 256;
#pragma unroll 4
    for (int j = 0; j < DH; ++j) acc += Ar[j] * cl[r][j];
#pragma unroll 4
    for (int j = 0; j < DH; ++j) acc += Ar[DH + j] * hl[r][j];
    al[r][i] = tanhf(acc);
  }
  __syncthreads();
  // GRU2
#pragma unroll
  for (int cc = 0; cc < 8; ++cc) {
    const int c = ci + 16 * cc;
    float ir = bih[c], iz = bih[DH + c], in_ = bih[2 * DH + c];
    float hr = bhh[c], hz = bhh[DH + c], hnv = bhh[2 * DH + c];
    const float* wi0 = wih + (size_t)c * DH;
    const float* wi1 = wih + (size_t)(DH + c) * DH;
    const float* wi2 = wih + (size_t)(2 * DH + c) * DH;
    const float* wh0 = whh + (size_t)c * DH;
    const float* wh1 = whh + (size_t)(DH + c) * DH;
    const float* wh2 = whh + (size_t)(2 * DH + c) * DH;
#pragma unroll 4
    for (int j = 0; j < DH; ++j) {
      const float av = al[r][j], hv = hl[r][j];
      ir += wi0[j] * av; iz += wi1[j] * av; in_ += wi2[j] * av;
      hr += wh0[j] * hv; hz += wh1[j] * hv; hnv += wh2[j] * hv;
    }
    const float rg = 1.f / (1.f + expf(-(ir + hr)));
    const float zg = 1.f / (1.f + expf(-(iz + hz)));
    const float ng = tanhf(in_ + rg * hnv);
    const float hv2 = (1.f - zg) * ng + zg * hl[r][c];
    hn[r][c] = hv2;
    h[(size_t)(b0 + r) * DH + c] = hv2;
  }
  __syncthreads();
  // out[:, t, :] = h_new @ out_w.T + out_b
#pragma unroll
  for (int oo = 0; oo < 2; ++oo) {
    const int o = ci + 16 * oo;
    float acc = outb[o];
#pragma unroll 4
    for (int j = 0; j < DH; ++j) acc += outw[o * DH + j] * hn[r][j];
    out[((size_t)(b0 + r) * NT + t) * DI + o] = acc;
  }
}

// ---------------- step 0: att1 (D=32) + GRU1 with h_rep = tile(fcn, 4)
__global__ __launch_bounds__(256) void k_main0(
    const float* __restrict__ enc, const float* __restrict__ fcn,
    const float* __restrict__ W0,
    const float* __restrict__ A1, const float* __restrict__ b1,
    const float* __restrict__ wih, const float* __restrict__ whh,
    const float* __restrict__ bih, const float* __restrict__ bhh,
    const float* __restrict__ outw, const float* __restrict__ outb,
    float* __restrict__ h, float* __restrict__ out) {
  __shared__ float Wl[DI][DH + 1];
  __shared__ float el[16][DH + 1];
  __shared__ float fl[16][DI + 1];
  __shared__ float cl[16][DI + 1];
  __shared__ float al[16][DI + 1];
  __shared__ float hn[16][DH + 1];
  const int b0 = blockIdx.x * 16, tid = threadIdx.x;
  for (int idx = tid; idx < DI * DH; idx += 256) Wl[idx >> 7][idx & 127] = W0[idx];
  for (int idx = tid; idx < 16 * DH; idx += 256) {
    int r = idx >> 7, c = idx & 127;
    el[r][c] = enc[((size_t)(b0 + r) * NT + 0) * DH + c];
  }
  for (int idx = tid; idx < 16 * DI; idx += 256) {
    int r = idx / DI, c = idx % DI;
    fl[r][c] = fcn[(size_t)(b0 + r) * DI + c];
  }
  __syncthreads();
  const int r = tid >> 4, ci = tid & 15;
  // context0 (16 x 32)
#pragma unroll
  for (int ii = 0; ii < 2; ++ii) {
    const int i = ci + 16 * ii;
    float acc = 0.f;
#pragma unroll 4
    for (int j = 0; j < DH; ++j) acc += Wl[i][j] * el[r][j];
    cl[r][i] = acc;
  }
  __syncthreads();
  // att0 = tanh([ctx0, fcn] @ att1_w.T + b1)
#pragma unroll
  for (int ii = 0; ii < 2; ++ii) {
    const int i = ci + 16 * ii;
    float acc = b1[i];
    const float* Ar = A1 + (size_t)i * (2 * DI);
#pragma unroll 4
    for (int k = 0; k < DI; ++k) acc += Ar[k] * cl[r][k];
#pragma unroll 4
    for (int k = 0; k < DI; ++k) acc += Ar[DI + k] * fl[r][k];
    al[r][i] = tanhf(acc);
  }
  __syncthreads();
  // GRU1: x = att0 (K=32), hidden = h_rep (tile of fcn, K=128)
#pragma unroll
  for (int cc = 0; cc < 8; ++cc) {
    const int c = ci + 16 * cc;
    float ir = bih[c], iz = bih[DH + c], in_ = bih[2 * DH + c];
    float hr = bhh[c], hz = bhh[DH + c], hnv = bhh[2 * DH + c];
    const float* wi0 = wih + (size_t)c * DI;
    const float* wi1 = wih + (size_t)(DH + c) * DI;
    const float* wi2 = wih + (size_t)(2 * DH + c) * DI;
#pragma unroll 4
    for (int k = 0; k < DI; ++k) {
      const float av = al[r][k];
      ir += wi0[k] * av; iz += wi1[k] * av; in_ += wi2[k] * av;
    }
    const float* wh0 = whh + (size_t)c * DH;
    const float* wh1 = whh + (size_t)(DH + c) * DH;
    const float* wh2 = whh + (size_t)(2 * DH + c) * DH;
#pragma unroll 4
    for (int j = 0; j < DH; ++j) {
      const float hv = fl[r][j & (DI - 1)];
      hr += wh0[j] * hv; hz += wh1[j] * hv; hnv += wh2[j] * hv;
    }
    const float rg = 1.f / (1.f + expf(-(ir + hr)));
    const float zg = 1.f / (1.f + expf(-(iz + hz)));
    const float ng = tanhf(in_ + rg * hnv);
    const float hv2 = (1.f - zg) * ng + zg * fl[r][c & (DI - 1)];
    hn[r][c] = hv2;
    h[(size_t)(b0 + r) * DH + c] = hv2;
  }
  __syncthreads();
#pragma unroll
  for (int oo = 0; oo < 2; ++oo) {
    const int o = ci + 16 * oo;
    float acc = outb[o];
#pragma unroll 4
    for (int j = 0; j < DH; ++j) acc += outw[o * DH + j] * hn[r][j];
    out[((size_t)(b0 + r) * NT + 0) * DI + o] = acc;
  }
}

extern "C" void kernel_launch(void* const* d_in, const int* in_sizes, int n_in,
                              void* d_out, int out_size, void* d_ws, size_t ws_size,
                              hipStream_t stream) {
  (void)in_sizes; (void)n_in; (void)out_size; (void)ws_size;
  const float* fcn  = (const float*)d_in[0];
  const float* enc  = (const float*)d_in[1];
  const float* a1w  = (const float*)d_in[2];
  const float* a1b  = (const float*)d_in[3];
  const float* a2w  = (const float*)d_in[4];
  const float* a2b  = (const float*)d_in[5];
  const float* w1ih = (const float*)d_in[6];
  const float* w1hh = (const float*)d_in[7];
  const float* b1ih = (const float*)d_in[8];
  const float* b1hh = (const float*)d_in[9];
  const float* w2ih = (const float*)d_in[10];
  const float* w2hh = (const float*)d_in[11];
  const float* b2ih = (const float*)d_in[12];
  const float* b2hh = (const float*)d_in[13];
  const float* outw = (const float*)d_in[14];
  const float* outb = (const float*)d_in[15];
  float* out = (float*)d_out;
  float* ws  = (float*)d_ws;

  float* h     = ws;                                   // 4096*128
  float* spart = ws + (size_t)BZ * DH;                 // 64*128*128
  float* Wbuf  = spart + (size_t)64 * DH * DH;         // 128*128

  // step 0
  k_scores<DI><<<64, 256, 0, stream>>>(fcn, enc, 0, spart);
  k_softmax<DI><<<DI, 128, 0, stream>>>(spart, Wbuf);
  k_main0<<<BZ / 16, 256, 0, stream>>>(enc, fcn, Wbuf, a1w, a1b,
                                       w1ih, w1hh, b1ih, b1hh, outw, outb, h, out);
  // steps 1..127
  for (int t = 1; t < NT; ++t) {
    k_scores<DH><<<64, 256, 0, stream>>>(h, enc, t, spart);
    k_softmax<DH><<<DH, 128, 0, stream>>>(spart, Wbuf);
    k_main<<<BZ / 16, 256, 0, stream>>>(enc, t, Wbuf, a2w, a2b,
                                        w2ih, w2hh, b2ih, b2hh, outw, outb, h, out);
  }
}

// Round 2
// 6860.241 us; speedup vs baseline: 5.2294x; 5.2294x over previous
//
#include <hip/hip_runtime.h>
#include <math.h>

#define BZ 4096
#define NT 128
#define DH 128
#define DI 32
#define LDW 132      // padded row stride (floats) for 128-wide LDS tiles
#define SCR_KS 2116  // scratch per-ks-plane stride (16*132 + 4)

__device__ __forceinline__ float4 ld4(const float* p) { return *(const float4*)p; }
__device__ __forceinline__ void st4(float* p, float4 v) { *(float4*)p = v; }
__device__ __forceinline__ float dot4(float4 w, float4 a) {
  return w.x*a.x + w.y*a.y + w.z*a.z + w.w*a.w;
}
__device__ __forceinline__ float sigm(float x) { return 1.f / (1.f + expf(-x)); }

// copy ROWS x 128 f32 tile (src row stride srcStride) into LDS rows of stride LDW
__device__ __forceinline__ void stage128(float* dst, const float* __restrict__ src,
                                         int rows, int srcStride, int tid) {
  const int n4 = rows * 32;
  for (int idx = tid; idx < n4; idx += 512) {
    const int r = idx >> 5, c4 = (idx & 31) << 2;
    st4(dst + r * LDW + c4, ld4(src + (size_t)r * srcStride + c4));
  }
}

// One matvec phase: dest[r][c] (+)= sum_k Wb[c][k] * act[r][k], r<16, c<128, k<128.
// 512 threads: ks=tid&7 (k-split), cg=(tid>>3)&15 (8 cols), r4=tid>>7 (4 rows).
// Wb is reused as the k-reduction scratch after the K-loop.
template<int ADD>
__device__ __forceinline__ void phase128(float* Wb, const float* act, float* dest, int tid) {
  const int ks = tid & 7, cg = (tid >> 3) & 15, r4 = tid >> 7;
  const int rbase = r4 * 4;
  float acc[4][8];
#pragma unroll
  for (int a = 0; a < 4; ++a)
#pragma unroll
    for (int b = 0; b < 8; ++b) acc[a][b] = 0.f;
#pragma unroll
  for (int ch = 0; ch < 4; ++ch) {
    const int k = ks * 4 + ch * 32;
    float4 av[4];
#pragma unroll
    for (int ri = 0; ri < 4; ++ri) av[ri] = ld4(act + (rbase + ri) * LDW + k);
#pragma unroll
    for (int i = 0; i < 8; ++i) {
      float4 w = ld4(Wb + (cg * 8 + i) * LDW + k);
#pragma unroll
      for (int ri = 0; ri < 4; ++ri) acc[ri][i] += dot4(w, av[ri]);
    }
  }
  __syncthreads();   // done reading Wb; it becomes scratch
#pragma unroll
  for (int ri = 0; ri < 4; ++ri) {
    st4(Wb + ks * SCR_KS + (rbase + ri) * LDW + cg * 8,
        make_float4(acc[ri][0], acc[ri][1], acc[ri][2], acc[ri][3]));
    st4(Wb + ks * SCR_KS + (rbase + ri) * LDW + cg * 8 + 4,
        make_float4(acc[ri][4], acc[ri][5], acc[ri][6], acc[ri][7]));
  }
  __syncthreads();
  const int fr = tid >> 5, fc = (tid & 31) << 2;
  float4 s = make_float4(0.f, 0.f, 0.f, 0.f);
#pragma unroll
  for (int kk = 0; kk < 8; ++kk) {
    float4 v = ld4(Wb + kk * SCR_KS + fr * LDW + fc);
    s.x += v.x; s.y += v.y; s.z += v.z; s.w += v.w;
  }
  float* dp = dest + fr * LDW + fc;
  if (ADD) { float4 o = ld4(dp); s.x += o.x; s.y += o.y; s.z += o.z; s.w += o.w; }
  st4(dp, s);
  __syncthreads();
}

// ---------------- scores partials: 128 blocks x 32 batch rows each
template<int D>
__global__ __launch_bounds__(512) void k_scores(const float* __restrict__ hsrc,
                                                const float* __restrict__ enc,
                                                int t, float* __restrict__ spart) {
  constexpr int IG = D / 8;    // i-groups of 8
  constexpr int JC = IG / 4;   // cols per thread (D=128 -> 4, D=32 -> 1)
  constexpr int HS = D + 4;
  __shared__ float hs[32 * HS];
  __shared__ float es[32 * LDW];
  const int p = blockIdx.x, tid = threadIdx.x, b0 = p * 32;
  for (int idx = tid; idx < 32 * (D / 4); idx += 512) {
    const int r = idx / (D / 4), c4 = (idx % (D / 4)) * 4;
    st4(hs + r * HS + c4, ld4(hsrc + (size_t)(b0 + r) * D + c4));
  }
  for (int idx = tid; idx < 32 * 32; idx += 512) {
    const int r = idx >> 5, c4 = (idx & 31) << 2;
    st4(es + r * LDW + c4, ld4(enc + ((size_t)(b0 + r) * NT + t) * DH + c4));
  }
  __syncthreads();
  const int ig = tid % IG, jg = tid / IG;
  const int i0 = ig * 8, j0 = jg * JC;
  float acc[8][JC];
#pragma unroll
  for (int a = 0; a < 8; ++a)
#pragma unroll
    for (int b = 0; b < JC; ++b) acc[a][b] = 0.f;
  for (int b = 0; b < 32; ++b) {
    float4 h0 = ld4(hs + b * HS + i0);
    float4 h1 = ld4(hs + b * HS + i0 + 4);
    float hv[8] = {h0.x, h0.y, h0.z, h0.w, h1.x, h1.y, h1.z, h1.w};
    float ev[JC];
    if (JC == 4) {
      float4 e = ld4(es + b * LDW + j0);
      ev[0] = e.x; ev[1] = e.y; ev[2] = e.z; ev[3] = e.w;
    } else {
      ev[0] = es[b * LDW + j0];
    }
#pragma unroll
    for (int ii = 0; ii < 8; ++ii)
#pragma unroll
      for (int jj = 0; jj < JC; ++jj) acc[ii][jj] += hv[ii] * ev[jj];
  }
#pragma unroll
  for (int ii = 0; ii < 8; ++ii)
#pragma unroll
    for (int jj = 0; jj < JC; ++jj)
      spart[((size_t)p * D + (i0 + ii)) * 128 + j0 + jj] = acc[ii][jj];
}

// ---------------- reduce 128 partials + row softmax
template<int R>
__global__ __launch_bounds__(128) void k_soft(const float* __restrict__ spart,
                                              float* __restrict__ W) {
  const int r = blockIdx.x, j = threadIdx.x;
  float s = 0.f;
#pragma unroll 8
  for (int p = 0; p < 128; ++p) s += spart[((size_t)p * R + r) * 128 + j];
  __shared__ float xm[2], xs[2];
  float m = s;
  for (int o = 1; o < 64; o <<= 1) m = fmaxf(m, __shfl_xor(m, o));
  if ((j & 63) == 0) xm[j >> 6] = m;
  __syncthreads();
  m = fmaxf(xm[0], xm[1]);
  float e = expf(s - m);
  float sum = e;
  for (int o = 1; o < 64; o <<= 1) sum += __shfl_xor(sum, o);
  if ((j & 63) == 0) xs[j >> 6] = sum;
  __syncthreads();
  sum = xs[0] + xs[1];
  W[r * 128 + j] = e / sum;
}

__device__ __forceinline__ void gru_out(float p0, float p1, float p2, float p3,
                                        float bi0, float bi1, float bi2,
                                        float bh0, float bh1, float bh2,
                                        float hv, float* o) {
  const float rg = sigm(p0 + bi0 + bh0);
  const float zg = sigm(p1 + bi1 + bh1);
  const float ng = tanhf(p2 + bi2 + rg * (p3 + bh2));
  *o = (1.f - zg) * ng + zg * hv;
}

// ---------------- main step t>=1
__global__ __launch_bounds__(512) void k_main(
    const float* __restrict__ enc, int t,
    const float* __restrict__ Wm,
    const float* __restrict__ A2, const float* __restrict__ b2,
    const float* __restrict__ wih, const float* __restrict__ whh,
    const float* __restrict__ bih, const float* __restrict__ bhh,
    const float* __restrict__ outw, const float* __restrict__ outb,
    float* __restrict__ h, float* __restrict__ out) {
  __shared__ float Wb[16960];
  __shared__ float el[16 * LDW], hl[16 * LDW], al[16 * LDW], hn[16 * LDW];
  __shared__ float pre[4][16 * LDW];
  const int tid = threadIdx.x, b0 = blockIdx.x * 16;
  {
    const int r = tid >> 5, c4 = (tid & 31) << 2;
    st4(el + r * LDW + c4, ld4(enc + ((size_t)(b0 + r) * NT + t) * DH + c4));
    st4(hl + r * LDW + c4, ld4(h + (size_t)(b0 + r) * DH + c4));
  }
  stage128(Wb, Wm, 128, 128, tid);
  __syncthreads();
  phase128<0>(Wb, el, hn, tid);                 // ctx -> hn (temp)
  stage128(Wb, A2, 128, 256, tid);              // A2[:,0:128]
  __syncthreads();
  phase128<0>(Wb, hn, pre[0], tid);             // a-pre (ctx part)
  stage128(Wb, A2 + 128, 128, 256, tid);        // A2[:,128:256]
  __syncthreads();
  phase128<1>(Wb, hl, pre[0], tid);             // a-pre += h part
  {
    const int fr = tid >> 5, fc = (tid & 31) << 2;
    float4 v = ld4(&pre[0][fr * LDW + fc]);
    float4 bb = ld4(b2 + fc);
    v.x = tanhf(v.x + bb.x); v.y = tanhf(v.y + bb.y);
    v.z = tanhf(v.z + bb.z); v.w = tanhf(v.w + bb.w);
    st4(al + fr * LDW + fc, v);
  }
  __syncthreads();
  stage128(Wb, wih, 128, 128, tid);               __syncthreads();
  phase128<0>(Wb, al, pre[0], tid);               // i_r
  stage128(Wb, whh, 128, 128, tid);               __syncthreads();
  phase128<1>(Wb, hl, pre[0], tid);               // + h_r
  stage128(Wb, wih + 16384, 128, 128, tid);       __syncthreads();
  phase128<0>(Wb, al, pre[1], tid);               // i_z
  stage128(Wb, whh + 16384, 128, 128, tid);       __syncthreads();
  phase128<1>(Wb, hl, pre[1], tid);               // + h_z
  stage128(Wb, wih + 32768, 128, 128, tid);       __syncthreads();
  phase128<0>(Wb, al, pre[2], tid);               // i_n
  stage128(Wb, whh + 32768, 128, 128, tid);       __syncthreads();
  phase128<0>(Wb, hl, pre[3], tid);               // h_n
  {
    const int fr = tid >> 5, fc = (tid & 31) << 2;
    float4 p0 = ld4(&pre[0][fr * LDW + fc]), p1 = ld4(&pre[1][fr * LDW + fc]);
    float4 p2 = ld4(&pre[2][fr * LDW + fc]), p3 = ld4(&pre[3][fr * LDW + fc]);
    float4 bi0 = ld4(bih + fc), bi1 = ld4(bih + DH + fc), bi2 = ld4(bih + 2 * DH + fc);
    float4 bh0 = ld4(bhh + fc), bh1 = ld4(bhh + DH + fc), bh2 = ld4(bhh + 2 * DH + fc);
    float4 hv = ld4(hl + fr * LDW + fc);
    float o0, o1, o2, o3;
    gru_out(p0.x, p1.x, p2.x, p3.x, bi0.x, bi1.x, bi2.x, bh0.x, bh1.x, bh2.x, hv.x, &o0);
    gru_out(p0.y, p1.y, p2.y, p3.y, bi0.y, bi1.y, bi2.y, bh0.y, bh1.y, bh2.y, hv.y, &o1);
    gru_out(p0.z, p1.z, p2.z, p3.z, bi0.z, bi1.z, bi2.z, bh0.z, bh1.z, bh2.z, hv.z, &o2);
    gru_out(p0.w, p1.w, p2.w, p3.w, bi0.w, bi1.w, bi2.w, bh0.w, bh1.w, bh2.w, hv.w, &o3);
    float4 hnew = make_float4(o0, o1, o2, o3);
    st4(hn + fr * LDW + fc, hnew);
    st4(h + (size_t)(b0 + fr) * DH + fc, hnew);
  }
  __syncthreads();
  stage128(Wb, outw, 32, 128, tid);
  __syncthreads();
  {
    const int r = tid >> 5, c = tid & 31;
    float acc = outb[c];
#pragma unroll 8
    for (int k4 = 0; k4 < 32; ++k4)
      acc += dot4(ld4(Wb + c * LDW + k4 * 4), ld4(hn + r * LDW + k4 * 4));
    out[((size_t)(b0 + r) * NT + t) * DI + c] = acc;
  }
}

// ---------------- step 0
__global__ __launch_bounds__(512) void k_main0(
    const float* __restrict__ enc, const float* __restrict__ fcn,
    const float* __restrict__ W0,
    const float* __restrict__ A1, const float* __restrict__ b1,
    const float* __restrict__ wih, const float* __restrict__ whh,
    const float* __restrict__ bih, const float* __restrict__ bhh,
    const float* __restrict__ outw, const float* __restrict__ outb,
    float* __restrict__ h, float* __restrict__ out) {
  __shared__ float Wb[16960];
  __shared__ float el[16 * LDW], hrep[16 * LDW], al[16 * LDW], hn[16 * LDW];
  __shared__ float pre[4][16 * LDW];
  __shared__ float fl[16 * 36];
  const int tid = threadIdx.x, b0 = blockIdx.x * 16;
  {
    const int r = tid >> 5, c4 = (tid & 31) << 2;
    st4(el + r * LDW + c4, ld4(enc + ((size_t)(b0 + r) * NT + 0) * DH + c4));
  }
  {
    const int r = tid >> 5, c = tid & 31;
    fl[r * 36 + c] = fcn[(size_t)(b0 + r) * DI + c];
  }
  __syncthreads();
  {
    const int r = tid >> 5, fc = (tid & 31) << 2;
    st4(hrep + r * LDW + fc, ld4(fl + r * 36 + (fc & 31)));
  }
  stage128(Wb, W0, 32, 128, tid);
  __syncthreads();
  {  // ctx0 -> hn cols 0..31
    const int r = tid >> 5, q = tid & 31;
    float acc = 0.f;
#pragma unroll 8
    for (int k4 = 0; k4 < 32; ++k4)
      acc += dot4(ld4(Wb + q * LDW + k4 * 4), ld4(el + r * LDW + k4 * 4));
    hn[r * LDW + q] = acc;
  }
  __syncthreads();
  for (int idx = tid; idx < 512; idx += 512) {  // stage A1 (32x64) stride 68
    const int r = idx >> 4, c4 = (idx & 15) << 2;
    st4(Wb + r * 68 + c4, ld4(A1 + r * 64 + c4));
  }
  __syncthreads();
  {  // att0 -> al cols 0..31
    const int r = tid >> 5, i = tid & 31;
    float acc = b1[i];
#pragma unroll
    for (int k4 = 0; k4 < 8; ++k4)
      acc += dot4(ld4(Wb + i * 68 + k4 * 4), ld4(hn + r * LDW + k4 * 4));
#pragma unroll
    for (int k4 = 0; k4 < 8; ++k4)
      acc += dot4(ld4(Wb + i * 68 + 32 + k4 * 4), ld4(fl + r * 36 + k4 * 4));
    al[r * LDW + i] = tanhf(acc);
  }
  __syncthreads();
  for (int idx = tid; idx < 384 * 8; idx += 512) {  // stage w1ih (384x32) stride 36
    const int r = idx >> 3, c4 = (idx & 7) << 2;
    st4(Wb + r * 36 + c4, ld4(wih + r * 32 + c4));
  }
  __syncthreads();
  {  // gru1 ih parts (K=32)
    const int r = tid >> 5, c0 = tid & 31;
#pragma unroll
    for (int m = 0; m < 12; ++m) {
      const int c = c0 + 32 * m, g = c >> 7, col = c & 127;
      float acc = 0.f;
#pragma unroll
      for (int k4 = 0; k4 < 8; ++k4)
        acc += dot4(ld4(Wb + c * 36 + k4 * 4), ld4(al + r * LDW + k4 * 4));
      pre[(g == 2) ? 2 : g][r * LDW + col] = acc;
    }
  }
  __syncthreads();
  stage128(Wb, whh, 128, 128, tid);          __syncthreads();
  phase128<1>(Wb, hrep, pre[0], tid);
  stage128(Wb, whh + 16384, 128, 128, tid);  __syncthreads();
  phase128<1>(Wb, hrep, pre[1], tid);
  stage128(Wb, whh + 32768, 128, 128, tid);  __syncthreads();
  phase128<0>(Wb, hrep, pre[3], tid);
  {
    const int fr = tid >> 5, fc = (tid & 31) << 2;
    float4 p0 = ld4(&pre[0][fr * LDW + fc]), p1 = ld4(&pre[1][fr * LDW + fc]);
    float4 p2 = ld4(&pre[2][fr * LDW + fc]), p3 = ld4(&pre[3][fr * LDW + fc]);
    float4 bi0 = ld4(bih + fc), bi1 = ld4(bih + DH + fc), bi2 = ld4(bih + 2 * DH + fc);
    float4 bh0 = ld4(bhh + fc), bh1 = ld4(bhh + DH + fc), bh2 = ld4(bhh + 2 * DH + fc);
    float4 hv = ld4(hrep + fr * LDW + fc);
    float o0, o1, o2, o3;
    gru_out(p0.x, p1.x, p2.x, p3.x, bi0.x, bi1.x, bi2.x, bh0.x, bh1.x, bh2.x, hv.x, &o0);
    gru_out(p0.y, p1.y, p2.y, p3.y, bi0.y, bi1.y, bi2.y, bh0.y, bh1.y, bh2.y, hv.y, &o1);
    gru_out(p0.z, p1.z, p2.z, p3.z, bi0.z, bi1.z, bi2.z, bh0.z, bh1.z, bh2.z, hv.z, &o2);
    gru_out(p0.w, p1.w, p2.w, p3.w, bi0.w, bi1.w, bi2.w, bh0.w, bh1.w, bh2.w, hv.w, &o3);
    float4 hnew = make_float4(o0, o1, o2, o3);
    st4(hn + fr * LDW + fc, hnew);
    st4(h + (size_t)(b0 + fr) * DH + fc, hnew);
  }
  __syncthreads();
  stage128(Wb, outw, 32, 128, tid);
  __syncthreads();
  {
    const int r = tid >> 5, c = tid & 31;
    float acc = outb[c];
#pragma unroll 8
    for (int k4 = 0; k4 < 32; ++k4)
      acc += dot4(ld4(Wb + c * LDW + k4 * 4), ld4(hn + r * LDW + k4 * 4));
    out[((size_t)(b0 + r) * NT + 0) * DI + c] = acc;
  }
}

extern "C" void kernel_launch(void* const* d_in, const int* in_sizes, int n_in,
                              void* d_out, int out_size, void* d_ws, size_t ws_size,
                              hipStream_t stream) {
  (void)in_sizes; (void)n_in; (void)out_size; (void)ws_size;
  const float* fcn  = (const float*)d_in[0];
  const float* enc  = (const float*)d_in[1];
  const float* a1w  = (const float*)d_in[2];
  const float* a1b  = (const float*)d_in[3];
  const float* a2w  = (const float*)d_in[4];
  const float* a2b  = (const float*)d_in[5];
  const float* w1ih = (const float*)d_in[6];
  const float* w1hh = (const float*)d_in[7];
  const float* b1ih = (const float*)d_in[8];
  const float* b1hh = (const float*)d_in[9];
  const float* w2ih = (const float*)d_in[10];
  const float* w2hh = (const float*)d_in[11];
  const float* b2ih = (const float*)d_in[12];
  const float* b2hh = (const float*)d_in[13];
  const float* outw = (const float*)d_in[14];
  const float* outb = (const float*)d_in[15];
  float* out = (float*)d_out;
  float* ws  = (float*)d_ws;

  float* h     = ws;                                   // 4096*128
  float* spart = ws + (size_t)BZ * DH;                 // 128*128*128
  float* Wbuf  = spart + (size_t)128 * DH * DH;        // 128*128

  // step 0
  k_scores<DI><<<128, 512, 0, stream>>>(fcn, enc, 0, spart);
  k_soft<DI><<<DI, 128, 0, stream>>>(spart, Wbuf);
  k_main0<<<BZ / 16, 512, 0, stream>>>(enc, fcn, Wbuf, a1w, a1b,
                                       w1ih, w1hh, b1ih, b1hh, outw, outb, h, out);
  // steps 1..127
  for (int t = 1; t < NT; ++t) {
    k_scores<DH><<<128, 512, 0, stream>>>(h, enc, t, spart);
    k_soft<DH><<<DH, 128, 0, stream>>>(spart, Wbuf);
    k_main<<<BZ / 16, 512, 0, stream>>>(enc, t, Wbuf, a2w, a2b,
                                        w2ih, w2hh, b2ih, b2hh, outw, outb, h, out);
  }
}

// Round 3
// 5780.635 us; speedup vs baseline: 6.2061x; 1.1868x over previous
//
#include <hip/hip_runtime.h>
#include <math.h>

#define BZ 4096
#define NT 128
#define DH 128
#define DI 32
#define LDW 132      // padded row stride (floats) for 128-wide fp32 LDS tiles
#define SCR_KS 2116  // scratch per-ks-plane stride (16*132 + 4)
#define SA 136       // bf16 act tile row stride (2-way-bank-free for frag reads)

typedef short bf16x8 __attribute__((ext_vector_type(8)));
typedef float f32x4 __attribute__((ext_vector_type(4)));

__device__ __forceinline__ float4 ld4(const float* p) { return *(const float4*)(p); }
__device__ __forceinline__ void st4(float* p, float4 v) { *(float4*)(p) = v; }
__device__ __forceinline__ float dot4(float4 w, float4 a) {
  return w.x*a.x + w.y*a.y + w.z*a.z + w.w*a.w;
}
__device__ __forceinline__ float sigm(float x) { return 1.f / (1.f + expf(-x)); }
__device__ __forceinline__ unsigned short f2b(float x) {
  unsigned u = __float_as_uint(x);
  u += 0x7FFFu + ((u >> 16) & 1u);
  return (unsigned short)(u >> 16);
}

// ---------------- weight prep: fp32 -> bf16 tiles [a2a|a2b|wihR|whhR|wihZ|whhZ|wihN|whhN|outw]
__global__ __launch_bounds__(512) void k_prep(const float* __restrict__ a2w,
                                              const float* __restrict__ wih,
                                              const float* __restrict__ whh,
                                              const float* __restrict__ outw,
                                              unsigned short* __restrict__ wbf) {
  const int idx = blockIdx.x * 512 + threadIdx.x;
  if (idx >= 135168) return;
  const int tile = idx >> 14, pos = idx & 16383;
  float v;
  if (tile == 0)      v = a2w[(pos >> 7) * 256 + (pos & 127)];
  else if (tile == 1) v = a2w[(pos >> 7) * 256 + 128 + (pos & 127)];
  else if (tile == 2) v = wih[pos];
  else if (tile == 3) v = whh[pos];
  else if (tile == 4) v = wih[16384 + pos];
  else if (tile == 5) v = whh[16384 + pos];
  else if (tile == 6) v = wih[32768 + pos];
  else if (tile == 7) v = whh[32768 + pos];
  else                v = outw[pos];
  wbf[idx] = f2b(v);
}

// ---------------- scores partials: 64 blocks x 64 batch rows
template<int D>
__global__ __launch_bounds__(512) void k_scores(const float* __restrict__ hsrc,
                                                const float* __restrict__ enc,
                                                int t, float* __restrict__ spart) {
  constexpr int IG = D / 8;
  constexpr int JC = (D == 128) ? 4 : 1;
  constexpr int HS = D + 4;
  __shared__ float hs[64 * HS];
  __shared__ float es[64 * LDW];
  const int p = blockIdx.x, tid = threadIdx.x, b0 = p * 64;
  for (int idx = tid; idx < 64 * (D / 4); idx += 512) {
    const int r = idx / (D / 4), c4 = (idx % (D / 4)) * 4;
    st4(hs + r * HS + c4, ld4(hsrc + (size_t)(b0 + r) * D + c4));
  }
  for (int idx = tid; idx < 64 * 32; idx += 512) {
    const int r = idx >> 5, c4 = (idx & 31) << 2;
    st4(es + r * LDW + c4, ld4(enc + ((size_t)(b0 + r) * NT + t) * DH + c4));
  }
  __syncthreads();
  const int ig = tid % IG, jg = tid / IG;
  const int i0 = ig * 8, j0 = jg * JC;
  float acc[8][JC];
#pragma unroll
  for (int a = 0; a < 8; ++a)
#pragma unroll
    for (int b = 0; b < JC; ++b) acc[a][b] = 0.f;
  for (int b = 0; b < 64; ++b) {
    float4 h0 = ld4(hs + b * HS + i0);
    float4 h1 = ld4(hs + b * HS + i0 + 4);
    float hv[8] = {h0.x, h0.y, h0.z, h0.w, h1.x, h1.y, h1.z, h1.w};
    float ev[JC];
    if (JC == 4) {
      float4 e = ld4(es + b * LDW + j0);
      ev[0] = e.x; ev[1] = e.y; ev[2] = e.z; ev[3] = e.w;
    } else {
      ev[0] = es[b * LDW + j0];
    }
#pragma unroll
    for (int ii = 0; ii < 8; ++ii)
#pragma unroll
      for (int jj = 0; jj < JC; ++jj) acc[ii][jj] += hv[ii] * ev[jj];
  }
#pragma unroll
  for (int ii = 0; ii < 8; ++ii)
#pragma unroll
    for (int jj = 0; jj < JC; ++jj)
      spart[((size_t)p * D + (i0 + ii)) * 128 + j0 + jj] = acc[ii][jj];
}

// ---------------- reduce 64 partials + row softmax -> fp32 W and bf16 W
template<int R>
__global__ __launch_bounds__(128) void k_soft(const float* __restrict__ spart,
                                              float* __restrict__ W,
                                              unsigned short* __restrict__ Wmb) {
  const int r = blockIdx.x, j = threadIdx.x;
  float s = 0.f;
#pragma unroll 8
  for (int p = 0; p < 64; ++p) s += spart[((size_t)p * R + r) * 128 + j];
  __shared__ float xm[2], xs[2];
  float m = s;
  for (int o = 1; o < 64; o <<= 1) m = fmaxf(m, __shfl_xor(m, o));
  if ((j & 63) == 0) xm[j >> 6] = m;
  __syncthreads();
  m = fmaxf(xm[0], xm[1]);
  float e = expf(s - m);
  float sum = e;
  for (int o = 1; o < 64; o <<= 1) sum += __shfl_xor(sum, o);
  if ((j & 63) == 0) xs[j >> 6] = sum;
  __syncthreads();
  sum = xs[0] + xs[1];
  const float val = e / sum;
  W[r * 128 + j] = val;
  Wmb[r * 128 + j] = f2b(val);
}

// ---------------- MFMA helpers for k_main
struct TileRegs { uint4 v[4]; };

__device__ __forceinline__ void loadT(TileRegs& tr, const unsigned short* __restrict__ s,
                                      int tid, int full) {
  const int r0 = tid >> 4, c8 = (tid & 15) * 8;
#pragma unroll
  for (int p = 0; p < 4; ++p)
    if (p == 0 || full) tr.v[p] = *(const uint4*)(s + (size_t)(r0 + 32 * p) * 128 + c8);
}
__device__ __forceinline__ void writeT(const TileRegs& tr, unsigned short* dst,
                                       int tid, int full) {
  const int r0 = tid >> 4, c = tid & 15;
#pragma unroll
  for (int p = 0; p < 4; ++p)
    if (p == 0 || full) {
      const int R = r0 + 32 * p;
      *(uint4*)((char*)dst + ((R * 256 + c * 16) ^ ((R & 7) << 4))) = tr.v[p];
    }
}
// out[r][c] += sum_k act[r][k] * W[c][k]; W tile swizzled, act tile stride SA
__device__ __forceinline__ void mm(f32x4& acc, const unsigned short* Wt,
                                   const unsigned short* act, int w, int l) {
  const int n = l & 15, g = l >> 4;
  const int R = w * 16 + n;
  const char* ab = (const char*)act + n * (2 * SA) + g * 16;
  const char* wb = (const char*)Wt;
  const int sw = (R & 7) << 4;
#pragma unroll
  for (int ks = 0; ks < 4; ++ks) {
    bf16x8 a = *(const bf16x8*)(ab + ks * 64);
    bf16x8 b = *(const bf16x8*)(wb + ((R * 256 + ks * 64 + g * 16) ^ sw));
    acc = __builtin_amdgcn_mfma_f32_16x16x32_bf16(a, b, acc, 0, 0, 0);
  }
}

// ---------------- main step t>=1 (bf16 MFMA pipeline)
__global__ __launch_bounds__(512) void k_main(
    const float* __restrict__ enc, int t,
    const unsigned short* __restrict__ Wmb, const unsigned short* __restrict__ wbf,
    const float* __restrict__ att2b,
    const float* __restrict__ bih, const float* __restrict__ bhh,
    const float* __restrict__ outb,
    float* __restrict__ h, float* __restrict__ out) {
  __shared__ __align__(16) unsigned short Wslot[2][16384];
  __shared__ __align__(16) unsigned short el[16 * SA], hl[16 * SA];
  __shared__ __align__(16) unsigned short ctxl[16 * SA], al[16 * SA], hnl[16 * SA];
  const int tid = threadIdx.x, b0 = blockIdx.x * 16;
  const int w = tid >> 6, l = tid & 63;
  const int c = w * 16 + (l & 15), g4 = l >> 4;

  TileRegs trN;
  {  // stage act tiles (fp32 -> bf16)
    const int r = tid >> 5, c4 = (tid & 31) << 2;
    float4 e = ld4(enc + ((size_t)(b0 + r) * NT + t) * DH + c4);
    float4 hv = ld4(h + (size_t)(b0 + r) * DH + c4);
    unsigned short* ep = el + r * SA + c4;
    ep[0] = f2b(e.x); ep[1] = f2b(e.y); ep[2] = f2b(e.z); ep[3] = f2b(e.w);
    unsigned short* hp = hl + r * SA + c4;
    hp[0] = f2b(hv.x); hp[1] = f2b(hv.y); hp[2] = f2b(hv.z); hp[3] = f2b(hv.w);
  }
  loadT(trN, Wmb, tid, 1);
  writeT(trN, Wslot[0], tid, 1);
  loadT(trN, wbf, tid, 1);                 // tile for ph1 (a2a)
  const float b2c = att2b[c];
  const float bihR = bih[c], bihZ = bih[DH + c], bihN = bih[2 * DH + c];
  const float bhhR = bhh[c], bhhZ = bhh[DH + c], bhhN = bhh[2 * DH + c];
  __syncthreads();

  f32x4 aC = {0.f, 0.f, 0.f, 0.f}, aA = aC, aR = aC, aZ = aC, aIN = aC, aHN = aC;

  // ph0: ctx = el @ Wm^T        (slot0)
  mm(aC, Wslot[0], el, w, l);
  writeT(trN, Wslot[1], tid, 1); loadT(trN, wbf + 1 * 16384, tid, 1);
#pragma unroll
  for (int j = 0; j < 4; ++j) ctxl[(g4 * 4 + j) * SA + c] = f2b(aC[j]);
  __syncthreads();
  // ph1: aA = ctx @ a2a^T       (slot1)
  mm(aA, Wslot[1], ctxl, w, l);
  writeT(trN, Wslot[0], tid, 1); loadT(trN, wbf + 2 * 16384, tid, 1);
  __syncthreads();
  // ph2: aA += h @ a2b^T        (slot0) ; al = tanh(aA + b2)
  mm(aA, Wslot[0], hl, w, l);
  writeT(trN, Wslot[1], tid, 1); loadT(trN, wbf + 3 * 16384, tid, 1);
#pragma unroll
  for (int j = 0; j < 4; ++j) al[(g4 * 4 + j) * SA + c] = f2b(tanhf(aA[j] + b2c));
  __syncthreads();
  // ph3: aR = al @ wihR^T       (slot1)
  mm(aR, Wslot[1], al, w, l);
  writeT(trN, Wslot[0], tid, 1); loadT(trN, wbf + 4 * 16384, tid, 1);
  __syncthreads();
  // ph4: aR += h @ whhR^T       (slot0)
  mm(aR, Wslot[0], hl, w, l);
  writeT(trN, Wslot[1], tid, 1); loadT(trN, wbf + 5 * 16384, tid, 1);
  __syncthreads();
  // ph5: aZ = al @ wihZ^T       (slot1)
  mm(aZ, Wslot[1], al, w, l);
  writeT(trN, Wslot[0], tid, 1); loadT(trN, wbf + 6 * 16384, tid, 1);
  __syncthreads();
  // ph6: aZ += h @ whhZ^T       (slot0)
  mm(aZ, Wslot[0], hl, w, l);
  writeT(trN, Wslot[1], tid, 1); loadT(trN, wbf + 7 * 16384, tid, 1);
  __syncthreads();
  // ph7: aIN = al @ wihN^T      (slot1)
  mm(aIN, Wslot[1], al, w, l);
  writeT(trN, Wslot[0], tid, 1); loadT(trN, wbf + 8 * 16384, tid, 0);  // outw, 32 rows
  __syncthreads();
  // ph8: aHN = h @ whhN^T       (slot0) ; gates; h_new
  mm(aHN, Wslot[0], hl, w, l);
  writeT(trN, Wslot[1], tid, 0);
#pragma unroll
  for (int j = 0; j < 4; ++j) {
    const int row = g4 * 4 + j;
    const float rg = sigm(aR[j] + bihR + bhhR);
    const float zg = sigm(aZ[j] + bihZ + bhhZ);
    const float ng = tanhf(aIN[j] + bihN + rg * (aHN[j] + bhhN));
    const float ho = h[(size_t)(b0 + row) * DH + c];
    const float hv = (1.f - zg) * ng + zg * ho;
    hnl[row * SA + c] = f2b(hv);
    h[(size_t)(b0 + row) * DH + c] = hv;
  }
  __syncthreads();
  // ph9: out = h_new @ outw^T   (slot1, waves 0-1 only)
  if (w < 2) {
    f32x4 aO = {0.f, 0.f, 0.f, 0.f};
    mm(aO, Wslot[1], hnl, w, l);
    const float ob = outb[c];
#pragma unroll
    for (int j = 0; j < 4; ++j) {
      const int row = g4 * 4 + j;
      out[((size_t)(b0 + row) * NT + t) * DI + c] = aO[j] + ob;
    }
  }
}

// ============ step-0 path (fp32, runs once) ============
__device__ __forceinline__ void stage128(float* dst, const float* __restrict__ src,
                                         int rows, int srcStride, int tid) {
  const int n4 = rows * 32;
  for (int idx = tid; idx < n4; idx += 512) {
    const int r = idx >> 5, c4 = (idx & 31) << 2;
    st4(dst + r * LDW + c4, ld4(src + (size_t)r * srcStride + c4));
  }
}
template<int ADD>
__device__ __forceinline__ void phase128(float* Wb, const float* act, float* dest, int tid) {
  const int ks = tid & 7, cg = (tid >> 3) & 15, r4 = tid >> 7;
  const int rbase = r4 * 4;
  float acc[4][8];
#pragma unroll
  for (int a = 0; a < 4; ++a)
#pragma unroll
    for (int b = 0; b < 8; ++b) acc[a][b] = 0.f;
#pragma unroll
  for (int ch = 0; ch < 4; ++ch) {
    const int k = ks * 4 + ch * 32;
    float4 av[4];
#pragma unroll
    for (int ri = 0; ri < 4; ++ri) av[ri] = ld4(act + (rbase + ri) * LDW + k);
#pragma unroll
    for (int i = 0; i < 8; ++i) {
      float4 wv = ld4(Wb + (cg * 8 + i) * LDW + k);
#pragma unroll
      for (int ri = 0; ri < 4; ++ri) acc[ri][i] += dot4(wv, av[ri]);
    }
  }
  __syncthreads();
#pragma unroll
  for (int ri = 0; ri < 4; ++ri) {
    st4(Wb + ks * SCR_KS + (rbase + ri) * LDW + cg * 8,
        make_float4(acc[ri][0], acc[ri][1], acc[ri][2], acc[ri][3]));
    st4(Wb + ks * SCR_KS + (rbase + ri) * LDW + cg * 8 + 4,
        make_float4(acc[ri][4], acc[ri][5], acc[ri][6], acc[ri][7]));
  }
  __syncthreads();
  const int fr = tid >> 5, fc = (tid & 31) << 2;
  float4 s = make_float4(0.f, 0.f, 0.f, 0.f);
#pragma unroll
  for (int kk = 0; kk < 8; ++kk) {
    float4 v = ld4(Wb + kk * SCR_KS + fr * LDW + fc);
    s.x += v.x; s.y += v.y; s.z += v.z; s.w += v.w;
  }
  float* dp = dest + fr * LDW + fc;
  if (ADD) { float4 o = ld4(dp); s.x += o.x; s.y += o.y; s.z += o.z; s.w += o.w; }
  st4(dp, s);
  __syncthreads();
}
__device__ __forceinline__ void gru_out(float p0, float p1, float p2, float p3,
                                        float bi0, float bi1, float bi2,
                                        float bh0, float bh1, float bh2,
                                        float hv, float* o) {
  const float rg = sigm(p0 + bi0 + bh0);
  const float zg = sigm(p1 + bi1 + bh1);
  const float ng = tanhf(p2 + bi2 + rg * (p3 + bh2));
  *o = (1.f - zg) * ng + zg * hv;
}
__global__ __launch_bounds__(512) void k_main0(
    const float* __restrict__ enc, const float* __restrict__ fcn,
    const float* __restrict__ W0,
    const float* __restrict__ A1, const float* __restrict__ b1,
    const float* __restrict__ wih, const float* __restrict__ whh,
    const float* __restrict__ bih, const float* __restrict__ bhh,
    const float* __restrict__ outw, const float* __restrict__ outb,
    float* __restrict__ h, float* __restrict__ out) {
  __shared__ float Wb[16960];
  __shared__ float el[16 * LDW], hrep[16 * LDW], al[16 * LDW], hn[16 * LDW];
  __shared__ float pre[4][16 * LDW];
  __shared__ float fl[16 * 36];
  const int tid = threadIdx.x, b0 = blockIdx.x * 16;
  {
    const int r = tid >> 5, c4 = (tid & 31) << 2;
    st4(el + r * LDW + c4, ld4(enc + ((size_t)(b0 + r) * NT + 0) * DH + c4));
  }
  {
    const int r = tid >> 5, cc = tid & 31;
    fl[r * 36 + cc] = fcn[(size_t)(b0 + r) * DI + cc];
  }
  __syncthreads();
  {
    const int r = tid >> 5, fc = (tid & 31) << 2;
    st4(hrep + r * LDW + fc, ld4(fl + r * 36 + (fc & 31)));
  }
  stage128(Wb, W0, 32, 128, tid);
  __syncthreads();
  {
    const int r = tid >> 5, q = tid & 31;
    float acc = 0.f;
#pragma unroll 8
    for (int k4 = 0; k4 < 32; ++k4)
      acc += dot4(ld4(Wb + q * LDW + k4 * 4), ld4(el + r * LDW + k4 * 4));
    hn[r * LDW + q] = acc;
  }
  __syncthreads();
  for (int idx = tid; idx < 512; idx += 512) {
    const int r = idx >> 4, c4 = (idx & 15) << 2;
    st4(Wb + r * 68 + c4, ld4(A1 + r * 64 + c4));
  }
  __syncthreads();
  {
    const int r = tid >> 5, i = tid & 31;
    float acc = b1[i];
#pragma unroll
    for (int k4 = 0; k4 < 8; ++k4)
      acc += dot4(ld4(Wb + i * 68 + k4 * 4), ld4(hn + r * LDW + k4 * 4));
#pragma unroll
    for (int k4 = 0; k4 < 8; ++k4)
      acc += dot4(ld4(Wb + i * 68 + 32 + k4 * 4), ld4(fl + r * 36 + k4 * 4));
    al[r * LDW + i] = tanhf(acc);
  }
  __syncthreads();
  for (int idx = tid; idx < 384 * 8; idx += 512) {
    const int r = idx >> 3, c4 = (idx & 7) << 2;
    st4(Wb + r * 36 + c4, ld4(wih + r * 32 + c4));
  }
  __syncthreads();
  {
    const int r = tid >> 5, c0 = tid & 31;
#pragma unroll
    for (int m = 0; m < 12; ++m) {
      const int cc = c0 + 32 * m, g = cc >> 7, col = cc & 127;
      float acc = 0.f;
#pragma unroll
      for (int k4 = 0; k4 < 8; ++k4)
        acc += dot4(ld4(Wb + cc * 36 + k4 * 4), ld4(al + r * LDW + k4 * 4));
      pre[(g == 2) ? 2 : g][r * LDW + col] = acc;
    }
  }
  __syncthreads();
  stage128(Wb, whh, 128, 128, tid);          __syncthreads();
  phase128<1>(Wb, hrep, pre[0], tid);
  stage128(Wb, whh + 16384, 128, 128, tid);  __syncthreads();
  phase128<1>(Wb, hrep, pre[1], tid);
  stage128(Wb, whh + 32768, 128, 128, tid);  __syncthreads();
  phase128<0>(Wb, hrep, pre[3], tid);
  {
    const int fr = tid >> 5, fc = (tid & 31) << 2;
    float4 p0 = ld4(&pre[0][fr * LDW + fc]), p1 = ld4(&pre[1][fr * LDW + fc]);
    float4 p2 = ld4(&pre[2][fr * LDW + fc]), p3 = ld4(&pre[3][fr * LDW + fc]);
    float4 bi0 = ld4(bih + fc), bi1 = ld4(bih + DH + fc), bi2 = ld4(bih + 2 * DH + fc);
    float4 bh0 = ld4(bhh + fc), bh1 = ld4(bhh + DH + fc), bh2 = ld4(bhh + 2 * DH + fc);
    float4 hv = ld4(hrep + fr * LDW + fc);
    float o0, o1, o2, o3;
    gru_out(p0.x, p1.x, p2.x, p3.x, bi0.x, bi1.x, bi2.x, bh0.x, bh1.x, bh2.x, hv.x, &o0);
    gru_out(p0.y, p1.y, p2.y, p3.y, bi0.y, bi1.y, bi2.y, bh0.y, bh1.y, bh2.y, hv.y, &o1);
    gru_out(p0.z, p1.z, p2.z, p3.z, bi0.z, bi1.z, bi2.z, bh0.z, bh1.z, bh2.z, hv.z, &o2);
    gru_out(p0.w, p1.w, p2.w, p3.w, bi0.w, bi1.w, bi2.w, bh0.w, bh1.w, bh2.w, hv.w, &o3);
    float4 hnew = make_float4(o0, o1, o2, o3);
    st4(hn + fr * LDW + fc, hnew);
    st4(h + (size_t)(b0 + fr) * DH + fc, hnew);
  }
  __syncthreads();
  stage128(Wb, outw, 32, 128, tid);
  __syncthreads();
  {
    const int r = tid >> 5, cc = tid & 31;
    float acc = outb[cc];
#pragma unroll 8
    for (int k4 = 0; k4 < 32; ++k4)
      acc += dot4(ld4(Wb + cc * LDW + k4 * 4), ld4(hn + r * LDW + k4 * 4));
    out[((size_t)(b0 + r) * NT + 0) * DI + cc] = acc;
  }
}

extern "C" void kernel_launch(void* const* d_in, const int* in_sizes, int n_in,
                              void* d_out, int out_size, void* d_ws, size_t ws_size,
                              hipStream_t stream) {
  (void)in_sizes; (void)n_in; (void)out_size; (void)ws_size;
  const float* fcn  = (const float*)d_in[0];
  const float* enc  = (const float*)d_in[1];
  const float* a1w  = (const float*)d_in[2];
  const float* a1b  = (const float*)d_in[3];
  const float* a2w  = (const float*)d_in[4];
  const float* a2b  = (const float*)d_in[5];
  const float* w1ih = (const float*)d_in[6];
  const float* w1hh = (const float*)d_in[7];
  const float* b1ih = (const float*)d_in[8];
  const float* b1hh = (const float*)d_in[9];
  const float* w2ih = (const float*)d_in[10];
  const float* w2hh = (const float*)d_in[11];
  const float* b2ih = (const float*)d_in[12];
  const float* b2hh = (const float*)d_in[13];
  const float* outw = (const float*)d_in[14];
  const float* outb = (const float*)d_in[15];
  float* out = (float*)d_out;
  float* ws  = (float*)d_ws;

  float* h     = ws;                                  // 524288 f32
  float* spart = ws + 524288;                         // 64*128*128 = 1048576 f32
  float* Wbuf  = ws + 1572864;                        // 16384 f32
  unsigned short* wbf = (unsigned short*)(ws + 1589248);   // 135168 bf16
  unsigned short* Wmb = (unsigned short*)(ws + 1656832);   // 16384 bf16

  k_prep<<<264, 512, 0, stream>>>(a2w, w2ih, w2hh, outw, wbf);

  // step 0 (fp32 path)
  k_scores<DI><<<64, 512, 0, stream>>>(fcn, enc, 0, spart);
  k_soft<DI><<<DI, 128, 0, stream>>>(spart, Wbuf, Wmb);
  k_main0<<<BZ / 16, 512, 0, stream>>>(enc, fcn, Wbuf, a1w, a1b,
                                       w1ih, w1hh, b1ih, b1hh, outw, outb, h, out);
  // steps 1..127 (bf16 MFMA path)
  for (int t = 1; t < NT; ++t) {
    k_scores<DH><<<64, 512, 0, stream>>>(h, enc, t, spart);
    k_soft<DH><<<DH, 128, 0, stream>>>(spart, Wbuf, Wmb);
    k_main<<<BZ / 16, 512, 0, stream>>>(enc, t, Wmb, wbf, a2b,
                                        b2ih, b2hh, outb, h, out);
  }
}

// Round 4
// 4493.708 us; speedup vs baseline: 7.9834x; 1.2864x over previous
//
#include <hip/hip_runtime.h>
#include <math.h>

#define BZ 4096
#define NT 128
#define DH 128
#define DI 32
#define LDW 132      // padded row stride (floats) for 128-wide fp32 LDS tiles
#define SCR_KS 2116  // scratch per-ks-plane stride (16*132 + 4)
#define SA 136       // bf16 act tile row stride
#define ST 40        // transposed tile stride (shorts), 80B = 16B-aligned

typedef short bf16x8 __attribute__((ext_vector_type(8)));
typedef float f32x4 __attribute__((ext_vector_type(4)));

__device__ __forceinline__ float4 ld4(const float* p) { return *(const float4*)(p); }
__device__ __forceinline__ void st4(float* p, float4 v) { *(float4*)(p) = v; }
__device__ __forceinline__ float dot4(float4 w, float4 a) {
  return w.x*a.x + w.y*a.y + w.z*a.z + w.w*a.w;
}
__device__ __forceinline__ float sigm(float x) { return 1.f / (1.f + expf(-x)); }
__device__ __forceinline__ unsigned short f2b(float x) {
  unsigned u = __float_as_uint(x);
  u += 0x7FFFu + ((u >> 16) & 1u);
  return (unsigned short)(u >> 16);
}

// ---------------- weight prep: fp32 -> bf16 tiles [a2a|a2b|wihR|whhR|wihZ|whhZ|wihN|whhN|outw]
__global__ __launch_bounds__(512) void k_prep(const float* __restrict__ a2w,
                                              const float* __restrict__ wih,
                                              const float* __restrict__ whh,
                                              const float* __restrict__ outw,
                                              unsigned short* __restrict__ wbf) {
  const int idx = blockIdx.x * 512 + threadIdx.x;
  if (idx >= 135168) return;
  const int tile = idx >> 14, pos = idx & 16383;
  float v;
  if (tile == 0)      v = a2w[(pos >> 7) * 256 + (pos & 127)];
  else if (tile == 1) v = a2w[(pos >> 7) * 256 + 128 + (pos & 127)];
  else if (tile == 2) v = wih[pos];
  else if (tile == 3) v = whh[pos];
  else if (tile == 4) v = wih[16384 + pos];
  else if (tile == 5) v = whh[16384 + pos];
  else if (tile == 6) v = wih[32768 + pos];
  else if (tile == 7) v = whh[32768 + pos];
  else                v = outw[pos];
  wbf[idx] = f2b(v);
}

// ---------------- scores partials (used for t=0 and t=1 only): 64 blocks x 64 rows
template<int D>
__global__ __launch_bounds__(512) void k_scores(const float* __restrict__ hsrc,
                                                const float* __restrict__ enc,
                                                int t, float* __restrict__ spart) {
  constexpr int IG = D / 8;
  constexpr int JC = (D == 128) ? 4 : 1;
  constexpr int HS = D + 4;
  __shared__ float hs[64 * HS];
  __shared__ float es[64 * LDW];
  const int p = blockIdx.x, tid = threadIdx.x, b0 = p * 64;
  for (int idx = tid; idx < 64 * (D / 4); idx += 512) {
    const int r = idx / (D / 4), c4 = (idx % (D / 4)) * 4;
    st4(hs + r * HS + c4, ld4(hsrc + (size_t)(b0 + r) * D + c4));
  }
  for (int idx = tid; idx < 64 * 32; idx += 512) {
    const int r = idx >> 5, c4 = (idx & 31) << 2;
    st4(es + r * LDW + c4, ld4(enc + ((size_t)(b0 + r) * NT + t) * DH + c4));
  }
  __syncthreads();
  const int ig = tid % IG, jg = tid / IG;
  const int i0 = ig * 8, j0 = jg * JC;
  float acc[8][JC];
#pragma unroll
  for (int a = 0; a < 8; ++a)
#pragma unroll
    for (int b = 0; b < JC; ++b) acc[a][b] = 0.f;
  for (int b = 0; b < 64; ++b) {
    float4 h0 = ld4(hs + b * HS + i0);
    float4 h1 = ld4(hs + b * HS + i0 + 4);
    float hv[8] = {h0.x, h0.y, h0.z, h0.w, h1.x, h1.y, h1.z, h1.w};
    float ev[JC];
    if (JC == 4) {
      float4 e = ld4(es + b * LDW + j0);
      ev[0] = e.x; ev[1] = e.y; ev[2] = e.z; ev[3] = e.w;
    } else {
      ev[0] = es[b * LDW + j0];
    }
#pragma unroll
    for (int ii = 0; ii < 8; ++ii)
#pragma unroll
      for (int jj = 0; jj < JC; ++jj) acc[ii][jj] += hv[ii] * ev[jj];
  }
#pragma unroll
  for (int ii = 0; ii < 8; ++ii)
#pragma unroll
    for (int jj = 0; jj < JC; ++jj)
      spart[((size_t)p * D + (i0 + ii)) * 128 + j0 + jj] = acc[ii][jj];
}

// ---------------- reduce P partials + row softmax -> fp32 W and bf16 W
template<int R, int P>
__global__ __launch_bounds__(128) void k_soft(const float* __restrict__ spart,
                                              float* __restrict__ W,
                                              unsigned short* __restrict__ Wmb) {
  const int r = blockIdx.x, j = threadIdx.x;
  float s = 0.f;
#pragma unroll 8
  for (int p = 0; p < P; ++p) s += spart[((size_t)p * R + r) * 128 + j];
  __shared__ float xm[2], xs[2];
  float m = s;
  for (int o = 1; o < 64; o <<= 1) m = fmaxf(m, __shfl_xor(m, o));
  if ((j & 63) == 0) xm[j >> 6] = m;
  __syncthreads();
  m = fmaxf(xm[0], xm[1]);
  float e = expf(s - m);
  float sum = e;
  for (int o = 1; o < 64; o <<= 1) sum += __shfl_xor(sum, o);
  if ((j & 63) == 0) xs[j >> 6] = sum;
  __syncthreads();
  sum = xs[0] + xs[1];
  const float val = e / sum;
  W[r * 128 + j] = val;
  Wmb[r * 128 + j] = f2b(val);
}

// ---------------- MFMA helpers
struct TileRegs { uint4 v[4]; };

__device__ __forceinline__ void loadT(TileRegs& tr, const unsigned short* __restrict__ s,
                                      int tid, int full) {
  const int r0 = tid >> 4, c8 = (tid & 15) * 8;
#pragma unroll
  for (int p = 0; p < 4; ++p)
    if (p == 0 || full) tr.v[p] = *(const uint4*)(s + (size_t)(r0 + 32 * p) * 128 + c8);
}
__device__ __forceinline__ void writeT(const TileRegs& tr, unsigned short* dst,
                                       int tid, int full) {
  const int r0 = tid >> 4, c = tid & 15;
#pragma unroll
  for (int p = 0; p < 4; ++p)
    if (p == 0 || full) {
      const int R = r0 + 32 * p;
      *(uint4*)((char*)dst + ((R * 256 + c * 16) ^ ((R & 7) << 4))) = tr.v[p];
    }
}
// 2-row-tile matvec: accA(rows 0-15), accB(rows 16-31), cols w*16..+16, K=128
__device__ __forceinline__ void mm32(f32x4& accA, f32x4& accB, const unsigned short* Wt,
                                     const unsigned short* act, int w, int l) {
  const int n = l & 15, g = l >> 4;
  const int R = w * 16 + n;
  const char* ab0 = (const char*)act + n * (2 * SA) + g * 16;
  const char* ab1 = ab0 + 16 * (2 * SA);
  const char* wb = (const char*)Wt;
  const int sw = (R & 7) << 4;
#pragma unroll
  for (int ks = 0; ks < 4; ++ks) {
    bf16x8 b = *(const bf16x8*)(wb + ((R * 256 + ks * 64 + g * 16) ^ sw));
    bf16x8 a0 = *(const bf16x8*)(ab0 + ks * 64);
    bf16x8 a1 = *(const bf16x8*)(ab1 + ks * 64);
    accA = __builtin_amdgcn_mfma_f32_16x16x32_bf16(a0, b, accA, 0, 0, 0);
    accB = __builtin_amdgcn_mfma_f32_16x16x32_bf16(a1, b, accB, 0, 0, 0);
  }
}

// ---------------- fused step t>=1: attend+GRU+out + scores partial for t+1
__global__ __launch_bounds__(512) void k_step(
    const float* __restrict__ enc, int t, int do_next,
    const unsigned short* __restrict__ Wmb, const unsigned short* __restrict__ wbf,
    const float* __restrict__ att2b,
    const float* __restrict__ bih, const float* __restrict__ bhh,
    const float* __restrict__ outb,
    float* __restrict__ h, float* __restrict__ out, float* __restrict__ spart) {
  __shared__ __align__(16) unsigned short Wslot[2][16384];
  __shared__ __align__(16) unsigned short el[32 * SA], hl[32 * SA];
  __shared__ __align__(16) unsigned short ctxl[32 * SA], al[32 * SA], hnl[32 * SA];
  __shared__ __align__(16) unsigned short hnT[128 * ST], encT[128 * ST];
  const int tid = threadIdx.x, b0 = blockIdx.x * 32;
  const int w = tid >> 6, l = tid & 63;
  const int n = l & 15, g4 = l >> 4;
  const int c = w * 16 + n;

  TileRegs trN;
  {  // stage el/hl (coalesced, r = tid>>4)
    const int r = tid >> 4, c8 = (tid & 15) << 3;
    float4 e0 = ld4(enc + ((size_t)(b0 + r) * NT + t) * DH + c8);
    float4 e1 = ld4(enc + ((size_t)(b0 + r) * NT + t) * DH + c8 + 4);
    float4 h0 = ld4(h + (size_t)(b0 + r) * DH + c8);
    float4 h1 = ld4(h + (size_t)(b0 + r) * DH + c8 + 4);
    unsigned short* ep = el + r * SA + c8;
    ep[0]=f2b(e0.x); ep[1]=f2b(e0.y); ep[2]=f2b(e0.z); ep[3]=f2b(e0.w);
    ep[4]=f2b(e1.x); ep[5]=f2b(e1.y); ep[6]=f2b(e1.z); ep[7]=f2b(e1.w);
    unsigned short* hp = hl + r * SA + c8;
    hp[0]=f2b(h0.x); hp[1]=f2b(h0.y); hp[2]=f2b(h0.z); hp[3]=f2b(h0.w);
    hp[4]=f2b(h1.x); hp[5]=f2b(h1.y); hp[6]=f2b(h1.z); hp[7]=f2b(h1.w);
  }
  if (do_next) {  // stage enc[:, t+1] transposed (r = tid&31 for LDS-bank spread)
    const int r = tid & 31, c8 = ((tid >> 5) & 15) << 3;
    float4 e0 = ld4(enc + ((size_t)(b0 + r) * NT + t + 1) * DH + c8);
    float4 e1 = ld4(enc + ((size_t)(b0 + r) * NT + t + 1) * DH + c8 + 4);
    encT[(c8 + 0) * ST + r] = f2b(e0.x); encT[(c8 + 1) * ST + r] = f2b(e0.y);
    encT[(c8 + 2) * ST + r] = f2b(e0.z); encT[(c8 + 3) * ST + r] = f2b(e0.w);
    encT[(c8 + 4) * ST + r] = f2b(e1.x); encT[(c8 + 5) * ST + r] = f2b(e1.y);
    encT[(c8 + 6) * ST + r] = f2b(e1.z); encT[(c8 + 7) * ST + r] = f2b(e1.w);
  }
  loadT(trN, Wmb, tid, 1);
  writeT(trN, Wslot[0], tid, 1);
  loadT(trN, wbf, tid, 1);
  const float b2c = att2b[c];
  const float bihR = bih[c], bihZ = bih[DH + c], bihN = bih[2 * DH + c];
  const float bhhR = bhh[c], bhhZ = bhh[DH + c], bhhN = bhh[2 * DH + c];
  __syncthreads();

  f32x4 z4 = {0.f, 0.f, 0.f, 0.f};
  f32x4 c0 = z4, c1 = z4, a0 = z4, a1 = z4, r0 = z4, r1 = z4;
  f32x4 zz0 = z4, zz1 = z4, in0 = z4, in1 = z4, hn0 = z4, hn1 = z4;

  // ph0: ctx = el @ Wm^T (s0)
  mm32(c0, c1, Wslot[0], el, w, l);
  writeT(trN, Wslot[1], tid, 1); loadT(trN, wbf + 16384, tid, 1);
#pragma unroll
  for (int j = 0; j < 4; ++j) {
    ctxl[(g4 * 4 + j) * SA + c] = f2b(c0[j]);
    ctxl[(16 + g4 * 4 + j) * SA + c] = f2b(c1[j]);
  }
  __syncthreads();
  // ph1: aA = ctx @ a2a^T (s1)
  mm32(a0, a1, Wslot[1], ctxl, w, l);
  writeT(trN, Wslot[0], tid, 1); loadT(trN, wbf + 2 * 16384, tid, 1);
  __syncthreads();
  // ph2: aA += h @ a2b^T (s0); al = tanh(aA + b2)
  mm32(a0, a1, Wslot[0], hl, w, l);
  writeT(trN, Wslot[1], tid, 1); loadT(trN, wbf + 3 * 16384, tid, 1);
#pragma unroll
  for (int j = 0; j < 4; ++j) {
    al[(g4 * 4 + j) * SA + c] = f2b(tanhf(a0[j] + b2c));
    al[(16 + g4 * 4 + j) * SA + c] = f2b(tanhf(a1[j] + b2c));
  }
  __syncthreads();
  // ph3: r = al @ wihR^T (s1)
  mm32(r0, r1, Wslot[1], al, w, l);
  writeT(trN, Wslot[0], tid, 1); loadT(trN, wbf + 4 * 16384, tid, 1);
  __syncthreads();
  // ph4: r += h @ whhR^T (s0)
  mm32(r0, r1, Wslot[0], hl, w, l);
  writeT(trN, Wslot[1], tid, 1); loadT(trN, wbf + 5 * 16384, tid, 1);
  __syncthreads();
  // ph5: z = al @ wihZ^T (s1)
  mm32(zz0, zz1, Wslot[1], al, w, l);
  writeT(trN, Wslot[0], tid, 1); loadT(trN, wbf + 6 * 16384, tid, 1);
  __syncthreads();
  // ph6: z += h @ whhZ^T (s0)
  mm32(zz0, zz1, Wslot[0], hl, w, l);
  writeT(trN, Wslot[1], tid, 1); loadT(trN, wbf + 7 * 16384, tid, 1);
  __syncthreads();
  // ph7: in = al @ wihN^T (s1)
  mm32(in0, in1, Wslot[1], al, w, l);
  writeT(trN, Wslot[0], tid, 1); loadT(trN, wbf + 8 * 16384, tid, 0);
  __syncthreads();
  // ph8: hn = h @ whhN^T (s0); gates; h_new -> global + hnl + hnT
  mm32(hn0, hn1, Wslot[0], hl, w, l);
  writeT(trN, Wslot[1], tid, 0);
#pragma unroll
  for (int half = 0; half < 2; ++half) {
    const f32x4& pr = half ? r1 : r0;
    const f32x4& pz = half ? zz1 : zz0;
    const f32x4& pi = half ? in1 : in0;
    const f32x4& ph = half ? hn1 : hn0;
#pragma unroll
    for (int j = 0; j < 4; ++j) {
      const int row = half * 16 + g4 * 4 + j;
      const float rg = sigm(pr[j] + bihR + bhhR);
      const float zg = sigm(pz[j] + bihZ + bhhZ);
      const float ng = tanhf(pi[j] + bihN + rg * (ph[j] + bhhN));
      const float ho = h[(size_t)(b0 + row) * DH + c];
      const float hv = (1.f - zg) * ng + zg * ho;
      const unsigned short hb = f2b(hv);
      hnl[row * SA + c] = hb;
      hnT[c * ST + row] = hb;
      h[(size_t)(b0 + row) * DH + c] = hv;
    }
  }
  __syncthreads();
  // ph9: out-proj (waves 0-1, s1 holds outw rows 0-31)
  if (w < 2) {
    f32x4 o0 = z4, o1 = z4;
    mm32(o0, o1, Wslot[1], hnl, w, l);
    const float ob = outb[c];
#pragma unroll
    for (int j = 0; j < 4; ++j) {
      out[((size_t)(b0 + g4 * 4 + j) * NT + t) * DI + c] = o0[j] + ob;
      out[((size_t)(b0 + 16 + g4 * 4 + j) * NT + t) * DI + c] = o1[j] + ob;
    }
  }
  // ph10: scores partial S_p[i][j] = sum_r hnT[i][r] * encT[j][r]  (K=32)
  if (do_next) {
    bf16x8 afr = *(const bf16x8*)(hnT + (16 * w + n) * ST + g4 * 8);
    float* spb = spart + ((size_t)blockIdx.x * 128 + 16 * w + g4 * 4) * 128 + n;
#pragma unroll
    for (int nt = 0; nt < 8; ++nt) {
      bf16x8 bfr = *(const bf16x8*)(encT + (16 * nt + n) * ST + g4 * 8);
      f32x4 s = z4;
      s = __builtin_amdgcn_mfma_f32_16x16x32_bf16(afr, bfr, s, 0, 0, 0);
#pragma unroll
      for (int jj = 0; jj < 4; ++jj) spb[(size_t)jj * 128 + 16 * nt] = s[jj];
    }
  }
}

// ============ step-0 path (fp32, runs once) ============
__device__ __forceinline__ void stage128(float* dst, const float* __restrict__ src,
                                         int rows, int srcStride, int tid) {
  const int n4 = rows * 32;
  for (int idx = tid; idx < n4; idx += 512) {
    const int r = idx >> 5, c4 = (idx & 31) << 2;
    st4(dst + r * LDW + c4, ld4(src + (size_t)r * srcStride + c4));
  }
}
template<int ADD>
__device__ __forceinline__ void phase128(float* Wb, const float* act, float* dest, int tid) {
  const int ks = tid & 7, cg = (tid >> 3) & 15, r4 = tid >> 7;
  const int rbase = r4 * 4;
  float acc[4][8];
#pragma unroll
  for (int a = 0; a < 4; ++a)
#pragma unroll
    for (int b = 0; b < 8; ++b) acc[a][b] = 0.f;
#pragma unroll
  for (int ch = 0; ch < 4; ++ch) {
    const int k = ks * 4 + ch * 32;
    float4 av[4];
#pragma unroll
    for (int ri = 0; ri < 4; ++ri) av[ri] = ld4(act + (rbase + ri) * LDW + k);
#pragma unroll
    for (int i = 0; i < 8; ++i) {
      float4 wv = ld4(Wb + (cg * 8 + i) * LDW + k);
#pragma unroll
      for (int ri = 0; ri < 4; ++ri) acc[ri][i] += dot4(wv, av[ri]);
    }
  }
  __syncthreads();
#pragma unroll
  for (int ri = 0; ri < 4; ++ri) {
    st4(Wb + ks * SCR_KS + (rbase + ri) * LDW + cg * 8,
        make_float4(acc[ri][0], acc[ri][1], acc[ri][2], acc[ri][3]));
    st4(Wb + ks * SCR_KS + (rbase + ri) * LDW + cg * 8 + 4,
        make_float4(acc[ri][4], acc[ri][5], acc[ri][6], acc[ri][7]));
  }
  __syncthreads();
  const int fr = tid >> 5, fc = (tid & 31) << 2;
  float4 s = make_float4(0.f, 0.f, 0.f, 0.f);
#pragma unroll
  for (int kk = 0; kk < 8; ++kk) {
    float4 v = ld4(Wb + kk * SCR_KS + fr * LDW + fc);
    s.x += v.x; s.y += v.y; s.z += v.z; s.w += v.w;
  }
  float* dp = dest + fr * LDW + fc;
  if (ADD) { float4 o = ld4(dp); s.x += o.x; s.y += o.y; s.z += o.z; s.w += o.w; }
  st4(dp, s);
  __syncthreads();
}
__device__ __forceinline__ void gru_out(float p0, float p1, float p2, float p3,
                                        float bi0, float bi1, float bi2,
                                        float bh0, float bh1, float bh2,
                                        float hv, float* o) {
  const float rg = sigm(p0 + bi0 + bh0);
  const float zg = sigm(p1 + bi1 + bh1);
  const float ng = tanhf(p2 + bi2 + rg * (p3 + bh2));
  *o = (1.f - zg) * ng + zg * hv;
}
__global__ __launch_bounds__(512) void k_main0(
    const float* __restrict__ enc, const float* __restrict__ fcn,
    const float* __restrict__ W0,
    const float* __restrict__ A1, const float* __restrict__ b1,
    const float* __restrict__ wih, const float* __restrict__ whh,
    const float* __restrict__ bih, const float* __restrict__ bhh,
    const float* __restrict__ outw, const float* __restrict__ outb,
    float* __restrict__ h, float* __restrict__ out) {
  __shared__ float Wb[16960];
  __shared__ float el[16 * LDW], hrep[16 * LDW], al[16 * LDW], hn[16 * LDW];
  __shared__ float pre[4][16 * LDW];
  __shared__ float fl[16 * 36];
  const int tid = threadIdx.x, b0 = blockIdx.x * 16;
  {
    const int r = tid >> 5, c4 = (tid & 31) << 2;
    st4(el + r * LDW + c4, ld4(enc + ((size_t)(b0 + r) * NT + 0) * DH + c4));
  }
  {
    const int r = tid >> 5, cc = tid & 31;
    fl[r * 36 + cc] = fcn[(size_t)(b0 + r) * DI + cc];
  }
  __syncthreads();
  {
    const int r = tid >> 5, fc = (tid & 31) << 2;
    st4(hrep + r * LDW + fc, ld4(fl + r * 36 + (fc & 31)));
  }
  stage128(Wb, W0, 32, 128, tid);
  __syncthreads();
  {
    const int r = tid >> 5, q = tid & 31;
    float acc = 0.f;
#pragma unroll 8
    for (int k4 = 0; k4 < 32; ++k4)
      acc += dot4(ld4(Wb + q * LDW + k4 * 4), ld4(el + r * LDW + k4 * 4));
    hn[r * LDW + q] = acc;
  }
  __syncthreads();
  for (int idx = tid; idx < 512; idx += 512) {
    const int r = idx >> 4, c4 = (idx & 15) << 2;
    st4(Wb + r * 68 + c4, ld4(A1 + r * 64 + c4));
  }
  __syncthreads();
  {
    const int r = tid >> 5, i = tid & 31;
    float acc = b1[i];
#pragma unroll
    for (int k4 = 0; k4 < 8; ++k4)
      acc += dot4(ld4(Wb + i * 68 + k4 * 4), ld4(hn + r * LDW + k4 * 4));
#pragma unroll
    for (int k4 = 0; k4 < 8; ++k4)
      acc += dot4(ld4(Wb + i * 68 + 32 + k4 * 4), ld4(fl + r * 36 + k4 * 4));
    al[r * LDW + i] = tanhf(acc);
  }
  __syncthreads();
  for (int idx = tid; idx < 384 * 8; idx += 512) {
    const int r = idx >> 3, c4 = (idx & 7) << 2;
    st4(Wb + r * 36 + c4, ld4(wih + r * 32 + c4));
  }
  __syncthreads();
  {
    const int r = tid >> 5, ccc = tid & 31;
#pragma unroll
    for (int m = 0; m < 12; ++m) {
      const int cc = ccc + 32 * m, g = cc >> 7, col = cc & 127;
      float acc = 0.f;
#pragma unroll
      for (int k4 = 0; k4 < 8; ++k4)
        acc += dot4(ld4(Wb + cc * 36 + k4 * 4), ld4(al + r * LDW + k4 * 4));
      pre[(g == 2) ? 2 : g][r * LDW + col] = acc;
    }
  }
  __syncthreads();
  stage128(Wb, whh, 128, 128, tid);          __syncthreads();
  phase128<1>(Wb, hrep, pre[0], tid);
  stage128(Wb, whh + 16384, 128, 128, tid);  __syncthreads();
  phase128<1>(Wb, hrep, pre[1], tid);
  stage128(Wb, whh + 32768, 128, 128, tid);  __syncthreads();
  phase128<0>(Wb, hrep, pre[3], tid);
  {
    const int fr = tid >> 5, fc = (tid & 31) << 2;
    float4 p0 = ld4(&pre[0][fr * LDW + fc]), p1 = ld4(&pre[1][fr * LDW + fc]);
    float4 p2 = ld4(&pre[2][fr * LDW + fc]), p3 = ld4(&pre[3][fr * LDW + fc]);
    float4 bi0 = ld4(bih + fc), bi1 = ld4(bih + DH + fc), bi2 = ld4(bih + 2 * DH + fc);
    float4 bh0 = ld4(bhh + fc), bh1 = ld4(bhh + DH + fc), bh2 = ld4(bhh + 2 * DH + fc);
    float4 hv = ld4(hrep + fr * LDW + fc);
    float o0, o1, o2, o3;
    gru_out(p0.x, p1.x, p2.x, p3.x, bi0.x, bi1.x, bi2.x, bh0.x, bh1.x, bh2.x, hv.x, &o0);
    gru_out(p0.y, p1.y, p2.y, p3.y, bi0.y, bi1.y, bi2.y, bh0.y, bh1.y, bh2.y, hv.y, &o1);
    gru_out(p0.z, p1.z, p2.z, p3.z, bi0.z, bi1.z, bi2.z, bh0.z, bh1.z, bh2.z, hv.z, &o2);
    gru_out(p0.w, p1.w, p2.w, p3.w, bi0.w, bi1.w, bi2.w, bh0.w, bh1.w, bh2.w, hv.w, &o3);
    float4 hnew = make_float4(o0, o1, o2, o3);
    st4(hn + fr * LDW + fc, hnew);
    st4(h + (size_t)(b0 + fr) * DH + fc, hnew);
  }
  __syncthreads();
  stage128(Wb, outw, 32, 128, tid);
  __syncthreads();
  {
    const int r = tid >> 5, cc = tid & 31;
    float acc = outb[cc];
#pragma unroll 8
    for (int k4 = 0; k4 < 32; ++k4)
      acc += dot4(ld4(Wb + cc * LDW + k4 * 4), ld4(hn + r * LDW + k4 * 4));
    out[((size_t)(b0 + r) * NT + 0) * DI + cc] = acc;
  }
}

extern "C" void kernel_launch(void* const* d_in, const int* in_sizes, int n_in,
                              void* d_out, int out_size, void* d_ws, size_t ws_size,
                              hipStream_t stream) {
  (void)in_sizes; (void)n_in; (void)out_size; (void)ws_size;
  const float* fcn  = (const float*)d_in[0];
  const float* enc  = (const float*)d_in[1];
  const float* a1w  = (const float*)d_in[2];
  const float* a1b  = (const float*)d_in[3];
  const float* a2w  = (const float*)d_in[4];
  const float* a2b  = (const float*)d_in[5];
  const float* w1ih = (const float*)d_in[6];
  const float* w1hh = (const float*)d_in[7];
  const float* b1ih = (const float*)d_in[8];
  const float* b1hh = (const float*)d_in[9];
  const float* w2ih = (const float*)d_in[10];
  const float* w2hh = (const float*)d_in[11];
  const float* b2ih = (const float*)d_in[12];
  const float* b2hh = (const float*)d_in[13];
  const float* outw = (const float*)d_in[14];
  const float* outb = (const float*)d_in[15];
  float* out = (float*)d_out;
  float* ws  = (float*)d_ws;

  float* h     = ws;                                       // 524288 f32
  float* spart = ws + 524288;                              // up to 128*128*128 f32 (8 MB)
  float* Wbuf  = ws + 524288 + 2097152;                    // 16384 f32
  unsigned short* wbf = (unsigned short*)(ws + 2637824);   // 135168 bf16
  unsigned short* Wmb = (unsigned short*)(ws + 2705408);   // 16384 bf16

  k_prep<<<264, 512, 0, stream>>>(a2w, w2ih, w2hh, outw, wbf);

  // step 0 (fp32 path)
  k_scores<DI><<<64, 512, 0, stream>>>(fcn, enc, 0, spart);
  k_soft<DI, 64><<<DI, 128, 0, stream>>>(spart, Wbuf, Wmb);
  k_main0<<<BZ / 16, 512, 0, stream>>>(enc, fcn, Wbuf, a1w, a1b,
                                       w1ih, w1hh, b1ih, b1hh, outw, outb, h, out);
  // bootstrap scores for t=1
  k_scores<DH><<<64, 512, 0, stream>>>(h, enc, 1, spart);
  k_soft<DH, 64><<<DH, 128, 0, stream>>>(spart, Wbuf, Wmb);
  // steps 1..127 (fused)
  for (int t = 1; t < NT; ++t) {
    k_step<<<BZ / 32, 512, 0, stream>>>(enc, t, (t < NT - 1) ? 1 : 0, Wmb, wbf, a2b,
                                        b2ih, b2hh, outb, h, out, spart);
    if (t < NT - 1)
      k_soft<DH, 128><<<DH, 128, 0, stream>>>(spart, Wbuf, Wmb);
  }
}